// Round 10
// baseline (26.475 us; speedup 1.0000x reference)
//
#include <hip/hip_runtime.h>

// 3x3 cross-correlation, padding=1, NCHW, fp32 in/out, bf16 MFMA compute.
// out[b,o,h,w] = bias[o] + sum_{i,c} comb[o, i*16+c] * x[b,c,h+dy_i,w+dx_i]
// B=4, C=16, O=16, H=450, W=480. K = 144 = 9 flows x 16 c, padded to 5x32.
//
// Round 10: concurrency via small blocks. R7/R9 (manual pipelines) both
// regressed; R8 (burst, 3 blocks/CU, 12 waves/CU) = 25.0us with all pipes
// idle -> thin-concurrency latency. Fix: 6 blocks/CU stagger phases
// naturally.
//  - ROUT=6 (450 = 75*6 exactly, no h tail), RSTG=8, WT=96
//  - LDS 26.6KB -> 6 blocks/CU; grid 1500 <= 1536 capacity, all resident
//  - float4 staging (8 planes x 4px per item): half the load insts of R8,
//    1.6 items/thread; 4-aligned quads fully in- or out-of-bounds
//  - 36 tiles round-robin over 4 waves (9 each), 5 MFMA per tile
//  - bijective XCD swizzle (1500 = 8*187+4), hg-fastest vertical strips

#define HH 450
#define WW 480
#define BB 4
#define CC 16
#define OO 16
#define WT    96                 // output pixels per block (width), 6 tiles
#define WQN   5                  // width groups
#define WIN   104                // staged wi count (w0-4 .. w0+99)
#define RSTG  8                  // staged rows per block
#define ROUT  6                  // output rows per block
#define HG    75                 // row-groups: 450/6 exactly
#define NTILE 6                  // 16-pixel MFMA tiles per row
#define W4N   26                 // float4 groups per staged row
#define HALF  (RSTG * W4N)       // 208 items per c-half
#define ITEMS (2 * HALF)         // 416 staging items
#define PLANE (RSTG * WIN)       // 832 LDS rows per c-half
#define NBLK  (BB * WQN * HG)    // 1500

typedef __attribute__((ext_vector_type(8))) short    bf16x8;
typedef __attribute__((ext_vector_type(4))) float    f32x4;
typedef __attribute__((ext_vector_type(4))) unsigned u32x4;

static __device__ __forceinline__ unsigned cvt_pk_bf16(float a, float b) {
    unsigned r;
    asm("v_cvt_pk_bf16_f32 %0, %1, %2" : "=v"(r) : "v"(a), "v"(b));
    return r;   // lo16 = bf16(a), hi16 = bf16(b), RNE
}

__global__ __launch_bounds__(256, 6) void flow_mfma_kernel(
    const float* __restrict__ x, const float* __restrict__ comb,
    const float* __restrict__ bias, float* __restrict__ out)
{
    // flat [2 c-half planes x 8 rows x 104 wi][8 shorts] : 26624 B
    __shared__ __align__(16) short xs[2 * PLANE][8];

    const int tid  = threadIdx.x;
    const int lane = tid & 63;
    const int wv   = tid >> 6;

    // ---- bijective XCD swizzle: 1500 = 8*187 + 4 (m204 formula) ----
    int bid = blockIdx.x;
    int xcd = bid & 7, pos = bid >> 3;
    int L   = (xcd < 4) ? xcd * 188 + pos : 4 * 188 + (xcd - 4) * 187 + pos;
    // decode: L = (b*WQN + wq)*HG + hg  (hg fastest -> vertical L2 strips)
    int hg  = L % HG;
    int t2  = L / HG;
    int wq  = t2 % WQN;
    int b   = t2 / WQN;
    int h0  = hg * ROUT;
    int w0  = wq * WT;

    // ---- A-frags: weights fp32->bf16 once, in VGPRs ----
    const int col = lane & 15;          // pixel-in-tile (B col) / output o (A row)
    const int grp = lane >> 4;          // 0..3
    bf16x8 af[5];
    #pragma unroll
    for (int m = 0; m < 5; ++m) {
        int k0 = m * 32 + grp * 8;
        u32x4 p;
        if (k0 < 144) {
            float4 u = *(const float4*)(comb + col * 144 + k0);
            float4 v = *(const float4*)(comb + col * 144 + k0 + 4);
            p[0] = cvt_pk_bf16(u.x, u.y);
            p[1] = cvt_pk_bf16(u.z, u.w);
            p[2] = cvt_pk_bf16(v.x, v.y);
            p[3] = cvt_pk_bf16(v.z, v.w);
        } else {
            p[0] = p[1] = p[2] = p[3] = 0u;
        }
        af[m] = __builtin_bit_cast(bf16x8, p);
    }
    f32x4 bv = *(const f32x4*)(bias + grp * 4);   // acc init: bias[grp*4+j]

    // ---- stage x -> LDS bf16 (float4 items: 8 planes x 4 pixels) ----
    auto stage = [&](int s) {
        int cs  = (s >= HALF) ? 1 : 0;
        int rem = s - cs * HALF;
        int r   = rem / W4N;              // 0..7
        int wi4 = rem - r * W4N;          // 0..25
        int hy  = h0 - 1 + r;
        int w   = w0 - 4 + wi4 * 4;
        u32x4 p[4];
        if (((unsigned)hy < (unsigned)HH) && ((unsigned)w < (unsigned)WW)) {
            const float* xp = x + (((size_t)(b * CC + cs * 8) * HH + hy) * WW + w);
            float4 v[8];
            #pragma unroll
            for (int j = 0; j < 8; ++j)
                v[j] = *(const float4*)(xp + (size_t)j * HH * WW);
            #pragma unroll
            for (int q = 0; q < 4; ++q) {
                p[0][q] = cvt_pk_bf16(v[2*q].x, v[2*q+1].x);
                p[1][q] = cvt_pk_bf16(v[2*q].y, v[2*q+1].y);
                p[2][q] = cvt_pk_bf16(v[2*q].z, v[2*q+1].z);
                p[3][q] = cvt_pk_bf16(v[2*q].w, v[2*q+1].w);
            }
        } else {
            #pragma unroll
            for (int k = 0; k < 4; ++k)
                p[k][0] = p[k][1] = p[k][2] = p[k][3] = 0u;
        }
        int r2 = cs * PLANE + r * WIN + wi4 * 4;
        #pragma unroll
        for (int k = 0; k < 4; ++k)
            *(u32x4*)(&xs[r2 + k][0]) = p[k];
    };
    stage(tid);
    if (tid < ITEMS - 256)                // tail: 160 items
        stage(tid + 256);
    __syncthreads();

    // ---- per-lane B-frag column offsets ----
    const int fo = grp >> 1;
    const int ch = grp & 1;
    int cof[5];
    #pragma unroll
    for (int m = 0; m < 4; ++m) {
        int i  = 2 * m + fo;
        int ky = i / 3;
        int kx = i - ky * 3;
        cof[m] = ch * PLANE + ky * WIN + col + kx + 3;
    }
    cof[4] = ch * PLANE + 2 * WIN + col + 5;   // flow 8 (ky=2, kx=2)

    // ---- compute: 36 tiles round-robin over 4 waves (no h tail: 450=75*6) --
    #pragma unroll
    for (int k = 0; k < 9; ++k) {
        int idx = wv + 4 * k;             // 0..35
        int row = idx / 6;                // 0..5
        int t   = idx - row * 6;          // 0..5
        int h   = h0 + row;
        int n0  = t * 16;
        int rbase = row * WIN + n0;
        f32x4 acc = bv;
        #pragma unroll
        for (int m = 0; m < 4; ++m) {
            bf16x8 bf = *(const bf16x8*)(&xs[rbase + cof[m]][0]);
            acc = __builtin_amdgcn_mfma_f32_16x16x32_bf16(af[m], bf, acc, 0, 0, 0);
        }
        bf16x8 b4;
        if (grp < 2) {
            b4 = *(const bf16x8*)(&xs[rbase + cof[4]][0]);
        } else {
            #pragma unroll
            for (int j = 0; j < 8; ++j) b4[j] = 0;
        }
        acc = __builtin_amdgcn_mfma_f32_16x16x32_bf16(af[4], b4, acc, 0, 0, 0);

        // D: col = pixel, o = grp*4 + j
        float* op = out + (((size_t)(b * OO + grp * 4) * HH + h) * WW + w0 + n0 + col);
        #pragma unroll
        for (int j = 0; j < 4; ++j)
            op[(size_t)j * HH * WW] = acc[j];
    }
}

extern "C" void kernel_launch(void* const* d_in, const int* in_sizes, int n_in,
                              void* d_out, int out_size, void* d_ws, size_t ws_size,
                              hipStream_t stream) {
    const float* x    = (const float*)d_in[0];
    const float* comb = (const float*)d_in[1];
    const float* bias = (const float*)d_in[2];
    float* out        = (float*)d_out;

    flow_mfma_kernel<<<NBLK, 256, 0, stream>>>(x, comb, bias, out);
}

// Round 11
// 26.044 us; speedup vs baseline: 1.0165x; 1.0165x over previous
//
#include <hip/hip_runtime.h>

// 3x3 cross-correlation, padding=1, NCHW, fp32 in/out, bf16 MFMA compute.
// out[b,o,h,w] = bias[o] + sum_{i,c} comb[o, i*16+c] * x[b,c,h+dy_i,w+dx_i]
// B=4, C=16, O=16, H=450, W=480. K = 144 = 9 flows x 16 c, padded to 5x32.
//
// Round 11: fewer/bigger blocks (session trend: R10 6/CU=26.5, R6 4/CU=26.4,
// R8 3/CU=25.0 -> extrapolate to 2/CU).
//  - ROUT=18 (450 = 25*18, no h tail), RSTG=20 -> halo 1.11x (best yet)
//  - LDS 66.6KB -> 2 blocks/CU; grid 500 <= 512 capacity, all resident
//  - float4 staging, ~4 items/thread fully unrolled (at 2 blocks/CU the
//    VGPR budget lets all staging loads fly concurrently)
//  - 108 tiles round-robin over 4 waves (27 each), 5 MFMA per tile
//  - bijective XCD swizzle (500 = 8*62+4), hg-fastest vertical strips

#define HH 450
#define WW 480
#define BB 4
#define CC 16
#define OO 16
#define WT    96                 // output pixels per block (width), 6 tiles
#define WQN   5                  // width groups
#define WIN   104                // staged wi count (w0-4 .. w0+99)
#define RSTG  20                 // staged rows per block
#define ROUT  18                 // output rows per block
#define HG    25                 // row-groups: 450/18 exactly
#define NTILE 6                  // 16-pixel MFMA tiles per row
#define W4N   26                 // float4 groups per staged row
#define HALF  (RSTG * W4N)       // 520 items per c-half
#define ITEMS (2 * HALF)         // 1040 staging items
#define PLANE (RSTG * WIN)       // 2080 LDS rows per c-half
#define NBLK  (BB * WQN * HG)    // 500

typedef __attribute__((ext_vector_type(8))) short    bf16x8;
typedef __attribute__((ext_vector_type(4))) float    f32x4;
typedef __attribute__((ext_vector_type(4))) unsigned u32x4;

static __device__ __forceinline__ unsigned cvt_pk_bf16(float a, float b) {
    unsigned r;
    asm("v_cvt_pk_bf16_f32 %0, %1, %2" : "=v"(r) : "v"(a), "v"(b));
    return r;   // lo16 = bf16(a), hi16 = bf16(b), RNE
}

__global__ __launch_bounds__(256, 2) void flow_mfma_kernel(
    const float* __restrict__ x, const float* __restrict__ comb,
    const float* __restrict__ bias, float* __restrict__ out)
{
    // flat [2 c-half planes x 20 rows x 104 wi][8 shorts] : 66560 B
    __shared__ __align__(16) short xs[2 * PLANE][8];

    const int tid  = threadIdx.x;
    const int lane = tid & 63;
    const int wv   = tid >> 6;

    // ---- bijective XCD swizzle: 500 = 8*62 + 4 (m204 formula) ----
    int bid = blockIdx.x;
    int xcd = bid & 7, pos = bid >> 3;
    int L   = (xcd < 4) ? xcd * 63 + pos : 4 * 63 + (xcd - 4) * 62 + pos;
    // decode: L = (b*WQN + wq)*HG + hg  (hg fastest -> vertical L2 strips)
    int hg  = L % HG;
    int t2  = L / HG;
    int wq  = t2 % WQN;
    int b   = t2 / WQN;
    int h0  = hg * ROUT;
    int w0  = wq * WT;

    // ---- A-frags: weights fp32->bf16 once, in VGPRs ----
    const int col = lane & 15;          // pixel-in-tile (B col) / output o (A row)
    const int grp = lane >> 4;          // 0..3
    bf16x8 af[5];
    #pragma unroll
    for (int m = 0; m < 5; ++m) {
        int k0 = m * 32 + grp * 8;
        u32x4 p;
        if (k0 < 144) {
            float4 u = *(const float4*)(comb + col * 144 + k0);
            float4 v = *(const float4*)(comb + col * 144 + k0 + 4);
            p[0] = cvt_pk_bf16(u.x, u.y);
            p[1] = cvt_pk_bf16(u.z, u.w);
            p[2] = cvt_pk_bf16(v.x, v.y);
            p[3] = cvt_pk_bf16(v.z, v.w);
        } else {
            p[0] = p[1] = p[2] = p[3] = 0u;
        }
        af[m] = __builtin_bit_cast(bf16x8, p);
    }
    f32x4 bv = *(const f32x4*)(bias + grp * 4);   // acc init: bias[grp*4+j]

    // ---- stage x -> LDS bf16 (float4 items: 8 planes x 4 pixels) ----
    auto stage = [&](int s) {
        int cs  = (s >= HALF) ? 1 : 0;
        int rem = s - cs * HALF;
        int r   = rem / W4N;              // 0..19
        int wi4 = rem - r * W4N;          // 0..25
        int hy  = h0 - 1 + r;
        int w   = w0 - 4 + wi4 * 4;
        u32x4 p[4];
        if (((unsigned)hy < (unsigned)HH) && ((unsigned)w < (unsigned)WW)) {
            const float* xp = x + (((size_t)(b * CC + cs * 8) * HH + hy) * WW + w);
            float4 v[8];
            #pragma unroll
            for (int j = 0; j < 8; ++j)
                v[j] = *(const float4*)(xp + (size_t)j * HH * WW);
            #pragma unroll
            for (int q = 0; q < 4; ++q) {
                p[0][q] = cvt_pk_bf16(v[2*q].x, v[2*q+1].x);
                p[1][q] = cvt_pk_bf16(v[2*q].y, v[2*q+1].y);
                p[2][q] = cvt_pk_bf16(v[2*q].z, v[2*q+1].z);
                p[3][q] = cvt_pk_bf16(v[2*q].w, v[2*q+1].w);
            }
        } else {
            #pragma unroll
            for (int k = 0; k < 4; ++k)
                p[k][0] = p[k][1] = p[k][2] = p[k][3] = 0u;
        }
        int r2 = cs * PLANE + r * WIN + wi4 * 4;
        #pragma unroll
        for (int k = 0; k < 4; ++k)
            *(u32x4*)(&xs[r2 + k][0]) = p[k];
    };
    #pragma unroll
    for (int it = 0; it < 4; ++it)        // 4*256 = 1024 items
        stage(tid + it * 256);
    if (tid < ITEMS - 4 * 256)            // tail: 16 items
        stage(tid + 4 * 256);
    __syncthreads();

    // ---- per-lane B-frag column offsets ----
    const int fo = grp >> 1;
    const int ch = grp & 1;
    int cof[5];
    #pragma unroll
    for (int m = 0; m < 4; ++m) {
        int i  = 2 * m + fo;
        int ky = i / 3;
        int kx = i - ky * 3;
        cof[m] = ch * PLANE + ky * WIN + col + kx + 3;
    }
    cof[4] = ch * PLANE + 2 * WIN + col + 5;   // flow 8 (ky=2, kx=2)

    // ---- compute: 108 tiles round-robin over 4 waves (no h tail) ----
    #pragma unroll
    for (int k = 0; k < 27; ++k) {
        int idx = wv + 4 * k;             // 0..107
        int row = idx / 6;                // 0..17
        int t   = idx - row * 6;          // 0..5
        int h   = h0 + row;
        int n0  = t * 16;
        int rbase = row * WIN + n0;
        f32x4 acc = bv;
        #pragma unroll
        for (int m = 0; m < 4; ++m) {
            bf16x8 bf = *(const bf16x8*)(&xs[rbase + cof[m]][0]);
            acc = __builtin_amdgcn_mfma_f32_16x16x32_bf16(af[m], bf, acc, 0, 0, 0);
        }
        bf16x8 b4;
        if (grp < 2) {
            b4 = *(const bf16x8*)(&xs[rbase + cof[4]][0]);
        } else {
            #pragma unroll
            for (int j = 0; j < 8; ++j) b4[j] = 0;
        }
        acc = __builtin_amdgcn_mfma_f32_16x16x32_bf16(af[4], b4, acc, 0, 0, 0);

        // D: col = pixel, o = grp*4 + j
        float* op = out + (((size_t)(b * OO + grp * 4) * HH + h) * WW + w0 + n0 + col);
        #pragma unroll
        for (int j = 0; j < 4; ++j)
            op[(size_t)j * HH * WW] = acc[j];
    }
}

extern "C" void kernel_launch(void* const* d_in, const int* in_sizes, int n_in,
                              void* d_out, int out_size, void* d_ws, size_t ws_size,
                              hipStream_t stream) {
    const float* x    = (const float*)d_in[0];
    const float* comb = (const float*)d_in[1];
    const float* bias = (const float*)d_in[2];
    float* out        = (float*)d_out;

    flow_mfma_kernel<<<NBLK, 256, 0, stream>>>(x, comb, bias, out);
}